// Round 4
// baseline (2699.552 us; speedup 1.0000x reference)
//
#include <hip/hip_runtime.h>

// Runtime-dtype-adaptive GCN. mode=1: inputs/outputs bf16; mode=0: float32.
// Forensics (r2: exact-zero output from bf16-interpretation NaN->relu->0) says
// the harness feeds float32; probe keeps us safe either way.

__device__ __forceinline__ float bf2f(unsigned short u) {
  union { unsigned u; float f; } c; c.u = ((unsigned)u) << 16; return c.f;
}
__device__ __forceinline__ unsigned short f2bf(float f) {
  union { float f; unsigned u; } c; c.f = f;
  unsigned x = c.u + 0x7fffu + ((c.u >> 16) & 1u);   // round-to-nearest-even
  return (unsigned short)(x >> 16);
}

// ---- dtype probe: bf16 elements have sane exponent fields; f32 low halves are
// mantissa garbage (uniform) ----
__global__ void k_probe(const void* __restrict__ x, int* __restrict__ mode) {
  __shared__ int cnt;
  if (threadIdx.x == 0) cnt = 0;
  __syncthreads();
  unsigned short u = ((const unsigned short*)x)[threadIdx.x * 2];
  int e = (u >> 7) & 0xff;
  if (e >= 100 && e <= 140) atomicAdd(&cnt, 1);
  __syncthreads();
  if (threadIdx.x == 0) mode[0] = (cnt >= 128) ? 1 : 0;
}

// convert a (possibly bf16) array to f32 scratch
__global__ void k_cvt(const void* __restrict__ in, float* __restrict__ out, int n,
                      const int* __restrict__ modep) {
  int i = blockIdx.x * 256 + threadIdx.x;
  if (i >= n) return;
  out[i] = (*modep) ? bf2f(((const unsigned short*)in)[i]) : ((const float*)in)[i];
}

__global__ void k_zero2(int* __restrict__ a, int* __restrict__ b, int n) {
  int i = blockIdx.x * 256 + threadIdx.x;
  if (i < n) { a[i] = 0; b[i] = 0; }
}

__global__ void k_count(const int* __restrict__ dst, int* __restrict__ cnt, int E) {
  int i = blockIdx.x * 256 + threadIdx.x;
  if (i < E) atomicAdd(&cnt[dst[i]], 1);
}

// single-block exclusive scan; 4096 elements per chunk (4/thread + Hillis-Steele on 1024 partials)
__global__ void k_scan(const int* __restrict__ cnt, int* __restrict__ rs, int n) {
  __shared__ int buf[1024];
  const int tid = threadIdx.x;
  int base = 0;
  for (int c0 = 0; c0 < n; c0 += 4096) {
    int i0 = c0 + tid * 4;
    int v[4], s = 0;
#pragma unroll
    for (int j = 0; j < 4; j++) {
      v[j] = (i0 + j < n) ? cnt[i0 + j] : 0;
      s += v[j];
    }
    __syncthreads();
    buf[tid] = s;
    __syncthreads();
    for (int off = 1; off < 1024; off <<= 1) {
      int t = 0;
      if (tid >= off) t = buf[tid - off];
      __syncthreads();
      buf[tid] += t;
      __syncthreads();
    }
    int incl = buf[tid];
    int tot  = buf[1023];
    int run  = base + incl - s;
#pragma unroll
    for (int j = 0; j < 4; j++) {
      if (i0 + j < n) rs[i0 + j] = run;
      run += v[j];
    }
    base += tot;
  }
  if (tid == 0) rs[n] = base;
}

__global__ void k_dinv(const int* __restrict__ cnt, float* __restrict__ dinv, int n) {
  int i = blockIdx.x * 256 + threadIdx.x;
  if (i < n) dinv[i] = rsqrtf((float)(cnt[i] + 1));   // +1 self-loop
}

__global__ void k_fill(const int* __restrict__ src, const int* __restrict__ dst,
                       const int* __restrict__ rs, int* __restrict__ cur,
                       int* __restrict__ csr, int E) {
  int i = blockIdx.x * 256 + threadIdx.x;
  if (i >= E) return;
  int d = dst[i];
  int pos = rs[d] + atomicAdd(&cur[d], 1);
  csr[pos] = src[i];
}

// ---- tiled VALU GEMM: C[M,NN] = A[M,KTOT] @ W[KTOT,NN] (f32 accum) ----
template<int KTOT, int NN, bool ABF16>
__global__ __launch_bounds__(256)
void k_gemm(const void* __restrict__ A, const float* __restrict__ W,
            float* __restrict__ Cc, int M, const int* __restrict__ modep) {
  constexpr int CPT = NN / 16;            // cols per thread (8 or 4)
  __shared__ float At[64 * 64];           // A slice, transposed [k][row]
  __shared__ float Wl[64 * NN];           // W slice [k][n]
  const int tid = threadIdx.x;
  const long row0 = (long)blockIdx.x * 64;
  const int rg = tid & 15;
  const int cg = tid >> 4;
  const int sr = tid >> 2;
  const int sq = tid & 3;
  const bool abf = ABF16 ? true : (*modep != 0);
  float acc[4][CPT];
#pragma unroll
  for (int i = 0; i < 4; i++)
#pragma unroll
    for (int c = 0; c < CPT; c++) acc[i][c] = 0.f;

  for (int k0 = 0; k0 < KTOT; k0 += 64) {
    { // stage A transposed
      float tmp[16];
      long row = row0 + sr;
      if (row < M) {
        if (abf) {
          const unsigned short* ap = (const unsigned short*)A + row * (long)KTOT + k0 + sq * 16;
          uint4 u0 = *(const uint4*)ap;
          uint4 u1 = *(const uint4*)(ap + 8);
          unsigned uu[8] = {u0.x, u0.y, u0.z, u0.w, u1.x, u1.y, u1.z, u1.w};
#pragma unroll
          for (int j = 0; j < 8; j++) {
            tmp[2 * j]     = bf2f((unsigned short)(uu[j] & 0xffffu));
            tmp[2 * j + 1] = bf2f((unsigned short)(uu[j] >> 16));
          }
        } else {
          const float* ap = (const float*)A + row * (long)KTOT + k0 + sq * 16;
          float4 f0 = *(const float4*)ap;       float4 f1 = *(const float4*)(ap + 4);
          float4 f2 = *(const float4*)(ap + 8); float4 f3 = *(const float4*)(ap + 12);
          tmp[0]=f0.x; tmp[1]=f0.y; tmp[2]=f0.z; tmp[3]=f0.w;
          tmp[4]=f1.x; tmp[5]=f1.y; tmp[6]=f1.z; tmp[7]=f1.w;
          tmp[8]=f2.x; tmp[9]=f2.y; tmp[10]=f2.z; tmp[11]=f2.w;
          tmp[12]=f3.x; tmp[13]=f3.y; tmp[14]=f3.z; tmp[15]=f3.w;
        }
      } else {
#pragma unroll
        for (int j = 0; j < 16; j++) tmp[j] = 0.f;
      }
#pragma unroll
      for (int j = 0; j < 16; j++) At[(sq * 16 + j) * 64 + sr] = tmp[j];
    }
    for (int i = tid * 4; i < 64 * NN; i += 1024)
      *(float4*)&Wl[i] = *(const float4*)(W + (long)k0 * NN + i);
    __syncthreads();
#pragma unroll 4
    for (int k = 0; k < 64; k++) {
      float4 a4 = *(const float4*)&At[k * 64 + rg * 4];
      float av[4] = {a4.x, a4.y, a4.z, a4.w};
#pragma unroll
      for (int b = 0; b < CPT / 4; b++) {
        float4 w4 = *(const float4*)&Wl[k * NN + cg * CPT + b * 4];
        float wv[4] = {w4.x, w4.y, w4.z, w4.w};
#pragma unroll
        for (int i = 0; i < 4; i++)
#pragma unroll
          for (int c = 0; c < 4; c++) acc[i][b * 4 + c] += av[i] * wv[c];
      }
    }
    __syncthreads();
  }
#pragma unroll
  for (int i = 0; i < 4; i++) {
    long row = row0 + rg * 4 + i;
    if (row < M) {
#pragma unroll
      for (int b = 0; b < CPT / 4; b++) {
        float4 o; o.x = acc[i][b*4]; o.y = acc[i][b*4+1]; o.z = acc[i][b*4+2]; o.w = acc[i][b*4+3];
        *(float4*)(Cc + row * NN + cg * CPT + b * 4) = o;
      }
    }
  }
}

// ---- CSR gather aggregation ----
template<int C, bool OUTBF>
__global__ void k_agg(const float* __restrict__ xw, const float* __restrict__ dinv,
                      const int* __restrict__ rs, const int* __restrict__ csr,
                      const float* __restrict__ bias, void* __restrict__ outp, int Nn) {
  int wid = (blockIdx.x * 256 + threadIdx.x) >> 6;
  int lane = threadIdx.x & 63;
  int n, ch;
  if (C == 128) { n = wid >> 1; ch = ((wid & 1) << 6) + lane; }
  else         { n = wid;      ch = lane; }
  if (n >= Nn) return;
  int p0 = rs[n], p1 = rs[n + 1];
  float acc = 0.f;
  for (int p = p0; p < p1; ++p) {
    int s = csr[p];
    acc += dinv[s] * xw[(long)s * C + ch];
  }
  float di = dinv[n];
  float v = fmaxf(di * acc + di * di * xw[(long)n * C + ch] + bias[ch], 0.f);
  if (OUTBF) ((unsigned short*)outp)[(long)n * C + ch] = f2bf(v);
  else       ((float*)outp)[(long)n * C + ch] = v;
}

// ---- fused edge scorer: wave per label row, W1 column cached in 64 VGPRs ----
__global__ __launch_bounds__(256)
void k_edge(const float* __restrict__ h2, const int* __restrict__ lab, int L,
            const float* __restrict__ w1f, const float* __restrict__ b1f,
            const float* __restrict__ w2f, const float* __restrict__ b2f,
            void* __restrict__ out, const int* __restrict__ modep) {
  const int lane = threadIdx.x & 63;
  int wslot = (blockIdx.x * 256 + threadIdx.x) >> 6;
  int wstride = (gridDim.x * 256) >> 6;
  float wcol[64];
#pragma unroll
  for (int k = 0; k < 64; k++) wcol[k] = w1f[k * 64 + lane];
  const float b1l = b1f[lane];
  const float w20 = w2f[lane * 2], w21 = w2f[lane * 2 + 1];
  const float ob0 = b2f[0], ob1 = b2f[1];
  const int md = *modep;
  for (long r = wslot; r < L; r += wstride) {
    int a = lab[r], b = lab[L + r];
    float e = h2[(long)a * 64 + lane] * h2[(long)b * 64 + lane];
    float a0 = 0.f, a1 = 0.f, a2 = 0.f, a3 = 0.f;
#pragma unroll
    for (int k = 0; k < 64; k += 4) {
      a0 += __shfl(e, k,     64) * wcol[k];
      a1 += __shfl(e, k + 1, 64) * wcol[k + 1];
      a2 += __shfl(e, k + 2, 64) * wcol[k + 2];
      a3 += __shfl(e, k + 3, 64) * wcol[k + 3];
    }
    float z = fmaxf((a0 + a1) + (a2 + a3) + b1l, 0.f);
    float p0 = z * w20, p1 = z * w21;
#pragma unroll
    for (int off = 32; off; off >>= 1) {
      p0 += __shfl_xor(p0, off, 64);
      p1 += __shfl_xor(p1, off, 64);
    }
    if (lane == 0) {
      if (md) {
        unsigned pack = (unsigned)f2bf(p0 + ob0) | ((unsigned)f2bf(p1 + ob1) << 16);
        ((unsigned*)out)[r] = pack;
      } else {
        float2 o; o.x = p0 + ob0; o.y = p1 + ob1;
        ((float2*)out)[r] = o;
      }
    }
  }
}

extern "C" void kernel_launch(void* const* d_in, const int* in_sizes, int n_in,
                              void* d_out, int out_size, void* d_ws, size_t ws_size,
                              hipStream_t stream) {
  const void* x    = d_in[0];
  const void* W1   = d_in[1];
  const void* b1   = d_in[2];
  const void* W2   = d_in[3];
  const void* b2   = d_in[4];
  const void* fcW1 = d_in[5];
  const void* fcb1 = d_in[6];
  const void* fcW2 = d_in[7];
  const void* fcb2 = d_in[8];
  const int* eidx = (const int*)d_in[9];
  const int* lidx = (const int*)d_in[10];

  const int Nn = in_sizes[0] / 512;   // 100000
  const int E  = in_sizes[9] / 2;     // 3200000
  const int L  = in_sizes[10] / 2;    // 1000000

  char* ws = (char*)d_ws;
  size_t off = 0;
  auto alloc = [&](size_t bytes) { size_t o = off; off += (bytes + 15) & ~(size_t)15; return o; };

  // seg0: xw1 f32 [N,128]; later reused as h2 f32 [N,64] (low) + hw2 f32 [N,64] (high)
  size_t o_seg0 = alloc((size_t)Nn * 128 * 4);
  float* xw1 = (float*)(ws + o_seg0);
  float* h2  = (float*)(ws + o_seg0);
  float* hw2 = (float*)(ws + o_seg0 + (size_t)Nn * 64 * 4);
  unsigned short* h1 = (unsigned short*)(ws + alloc((size_t)Nn * 128 * 2));
  int*   cnts = (int*)(ws + alloc((size_t)Nn * 4));
  int*   rs   = (int*)(ws + alloc((size_t)(Nn + 1) * 4));
  int*   cur  = (int*)(ws + alloc((size_t)Nn * 4));
  int*   csr  = (int*)(ws + alloc((size_t)E * 4));
  float* dinv = (float*)(ws + alloc((size_t)Nn * 4));
  float* W1f   = (float*)(ws + alloc(512 * 128 * 4));
  float* W2f   = (float*)(ws + alloc(128 * 64 * 4));
  float* fcW1f = (float*)(ws + alloc(64 * 64 * 4));
  float* fcW2f = (float*)(ws + alloc(64 * 2 * 4));
  float* b1f   = (float*)(ws + alloc(128 * 4));
  float* b2f   = (float*)(ws + alloc(64 * 4));
  float* fcb1f = (float*)(ws + alloc(64 * 4));
  float* fcb2f = (float*)(ws + alloc(16));
  int*   mode  = (int*)(ws + alloc(16));

  // 1. dtype probe
  k_probe<<<1, 256, 0, stream>>>(x, mode);
  // 2. weight/bias conversion to f32
  k_cvt<<<(512 * 128 + 255) / 256, 256, 0, stream>>>(W1, W1f, 512 * 128, mode);
  k_cvt<<<(128 * 64 + 255) / 256, 256, 0, stream>>>(W2, W2f, 128 * 64, mode);
  k_cvt<<<(64 * 64 + 255) / 256, 256, 0, stream>>>(fcW1, fcW1f, 64 * 64, mode);
  k_cvt<<<1, 256, 0, stream>>>(fcW2, fcW2f, 64 * 2, mode);
  k_cvt<<<1, 256, 0, stream>>>(b1, b1f, 128, mode);
  k_cvt<<<1, 256, 0, stream>>>(b2, b2f, 64, mode);
  k_cvt<<<1, 256, 0, stream>>>(fcb1, fcb1f, 64, mode);
  k_cvt<<<1, 256, 0, stream>>>(fcb2, fcb2f, 2, mode);
  // 3. CSR build (int atomics only)
  k_zero2<<<(Nn + 255) / 256, 256, 0, stream>>>(cnts, cur, Nn);
  k_count<<<(E + 255) / 256, 256, 0, stream>>>(eidx + E, cnts, E);
  k_scan<<<1, 1024, 0, stream>>>(cnts, rs, Nn);
  k_dinv<<<(Nn + 255) / 256, 256, 0, stream>>>(cnts, dinv, Nn);
  k_fill<<<(E + 255) / 256, 256, 0, stream>>>(eidx, eidx + E, rs, cur, csr, E);

  const int gB = (Nn + 63) / 64;
  // 4. layer 1
  k_gemm<512, 128, false><<<gB, 256, 0, stream>>>(x, W1f, xw1, Nn, mode);
  k_agg<128, true><<<(2 * Nn * 64 + 255) / 256, 256, 0, stream>>>(xw1, dinv, rs, csr, b1f, h1, Nn);
  // 5. layer 2
  k_gemm<128, 64, true><<<gB, 256, 0, stream>>>(h1, W2f, hw2, Nn, mode);
  k_agg<64, false><<<(Nn * 64 + 255) / 256, 256, 0, stream>>>(hw2, dinv, rs, csr, b2f, h2, Nn);
  // 6. edge scorer
  k_edge<<<2048, 256, 0, stream>>>(h2, lidx, L, fcW1f, fcb1f, fcW2f, fcb2f, d_out, mode);
}

// Round 5
// 1267.808 us; speedup vs baseline: 2.1293x; 2.1293x over previous
//
#include <hip/hip_runtime.h>

// Runtime-dtype-adaptive GCN. mode=1: inputs/outputs bf16; mode=0: float32.
// R4 measured: k_edge (shuffle MLP) = 41% of 2.7ms, latency-bound (VALUBusy 15%,
// HBM 3%). R5: k_edge -> MFMA (16 rows/wave, no fc1 shuffles); k_agg unroll x4.

typedef short s16x8 __attribute__((ext_vector_type(8)));   // 8 bf16 bit patterns
typedef float f32x4 __attribute__((ext_vector_type(4)));

__device__ __forceinline__ float bf2f(unsigned short u) {
  union { unsigned u; float f; } c; c.u = ((unsigned)u) << 16; return c.f;
}
__device__ __forceinline__ unsigned short f2bf(float f) {
  union { float f; unsigned u; } c; c.f = f;
  unsigned x = c.u + 0x7fffu + ((c.u >> 16) & 1u);   // round-to-nearest-even
  return (unsigned short)(x >> 16);
}

// ---- dtype probe ----
__global__ void k_probe(const void* __restrict__ x, int* __restrict__ mode) {
  __shared__ int cnt;
  if (threadIdx.x == 0) cnt = 0;
  __syncthreads();
  unsigned short u = ((const unsigned short*)x)[threadIdx.x * 2];
  int e = (u >> 7) & 0xff;
  if (e >= 100 && e <= 140) atomicAdd(&cnt, 1);
  __syncthreads();
  if (threadIdx.x == 0) mode[0] = (cnt >= 128) ? 1 : 0;
}

__global__ void k_cvt(const void* __restrict__ in, float* __restrict__ out, int n,
                      const int* __restrict__ modep) {
  int i = blockIdx.x * 256 + threadIdx.x;
  if (i >= n) return;
  out[i] = (*modep) ? bf2f(((const unsigned short*)in)[i]) : ((const float*)in)[i];
}

// swizzle f32 W[k][n] -> bf16 MFMA B-fragment order
// slot ((t*ksteps+s)*64+l)*8+j  <-  W[k=s*32+(l>>4)*8+j][n=t*16+(l&15)]
__global__ void k_swz_bf(const float* __restrict__ W, unsigned short* __restrict__ out,
                         int N, int ksteps, int total) {
  int i = blockIdx.x * 256 + threadIdx.x;
  if (i >= total) return;
  int j = i & 7, l = (i >> 3) & 63, ts = i >> 9;
  int s = ts % ksteps, t = ts / ksteps;
  int k = s * 32 + ((l >> 4) << 3) + j;
  int n = t * 16 + (l & 15);
  out[i] = f2bf(W[k * N + n]);
}

__global__ void k_zero2(int* __restrict__ a, int* __restrict__ b, int n) {
  int i = blockIdx.x * 256 + threadIdx.x;
  if (i < n) { a[i] = 0; b[i] = 0; }
}

__global__ void k_count(const int* __restrict__ dst, int* __restrict__ cnt, int E) {
  int i = blockIdx.x * 256 + threadIdx.x;
  if (i < E) atomicAdd(&cnt[dst[i]], 1);
}

// single-block exclusive scan; 4096 elems/chunk
__global__ void k_scan(const int* __restrict__ cnt, int* __restrict__ rs, int n) {
  __shared__ int buf[1024];
  const int tid = threadIdx.x;
  int base = 0;
  for (int c0 = 0; c0 < n; c0 += 4096) {
    int i0 = c0 + tid * 4;
    int v[4], s = 0;
#pragma unroll
    for (int j = 0; j < 4; j++) { v[j] = (i0 + j < n) ? cnt[i0 + j] : 0; s += v[j]; }
    __syncthreads();
    buf[tid] = s;
    __syncthreads();
    for (int off = 1; off < 1024; off <<= 1) {
      int t = 0;
      if (tid >= off) t = buf[tid - off];
      __syncthreads();
      buf[tid] += t;
      __syncthreads();
    }
    int incl = buf[tid];
    int tot  = buf[1023];
    int run  = base + incl - s;
#pragma unroll
    for (int j = 0; j < 4; j++) { if (i0 + j < n) rs[i0 + j] = run; run += v[j]; }
    base += tot;
  }
  if (tid == 0) rs[n] = base;
}

__global__ void k_dinv(const int* __restrict__ cnt, float* __restrict__ dinv, int n) {
  int i = blockIdx.x * 256 + threadIdx.x;
  if (i < n) dinv[i] = rsqrtf((float)(cnt[i] + 1));
}

__global__ void k_fill(const int* __restrict__ src, const int* __restrict__ dst,
                       const int* __restrict__ rs, int* __restrict__ cur,
                       int* __restrict__ csr, int E) {
  int i = blockIdx.x * 256 + threadIdx.x;
  if (i >= E) return;
  int d = dst[i];
  int pos = rs[d] + atomicAdd(&cur[d], 1);
  csr[pos] = src[i];
}

// ---- tiled VALU GEMM (unchanged from passing r4) ----
template<int KTOT, int NN, bool ABF16>
__global__ __launch_bounds__(256)
void k_gemm(const void* __restrict__ A, const float* __restrict__ W,
            float* __restrict__ Cc, int M, const int* __restrict__ modep) {
  constexpr int CPT = NN / 16;
  __shared__ float At[64 * 64];
  __shared__ float Wl[64 * NN];
  const int tid = threadIdx.x;
  const long row0 = (long)blockIdx.x * 64;
  const int rg = tid & 15;
  const int cg = tid >> 4;
  const int sr = tid >> 2;
  const int sq = tid & 3;
  const bool abf = ABF16 ? true : (*modep != 0);
  float acc[4][CPT];
#pragma unroll
  for (int i = 0; i < 4; i++)
#pragma unroll
    for (int c = 0; c < CPT; c++) acc[i][c] = 0.f;

  for (int k0 = 0; k0 < KTOT; k0 += 64) {
    {
      float tmp[16];
      long row = row0 + sr;
      if (row < M) {
        if (abf) {
          const unsigned short* ap = (const unsigned short*)A + row * (long)KTOT + k0 + sq * 16;
          uint4 u0 = *(const uint4*)ap;
          uint4 u1 = *(const uint4*)(ap + 8);
          unsigned uu[8] = {u0.x, u0.y, u0.z, u0.w, u1.x, u1.y, u1.z, u1.w};
#pragma unroll
          for (int j = 0; j < 8; j++) {
            tmp[2 * j]     = bf2f((unsigned short)(uu[j] & 0xffffu));
            tmp[2 * j + 1] = bf2f((unsigned short)(uu[j] >> 16));
          }
        } else {
          const float* ap = (const float*)A + row * (long)KTOT + k0 + sq * 16;
          float4 f0 = *(const float4*)ap;       float4 f1 = *(const float4*)(ap + 4);
          float4 f2 = *(const float4*)(ap + 8); float4 f3 = *(const float4*)(ap + 12);
          tmp[0]=f0.x; tmp[1]=f0.y; tmp[2]=f0.z; tmp[3]=f0.w;
          tmp[4]=f1.x; tmp[5]=f1.y; tmp[6]=f1.z; tmp[7]=f1.w;
          tmp[8]=f2.x; tmp[9]=f2.y; tmp[10]=f2.z; tmp[11]=f2.w;
          tmp[12]=f3.x; tmp[13]=f3.y; tmp[14]=f3.z; tmp[15]=f3.w;
        }
      } else {
#pragma unroll
        for (int j = 0; j < 16; j++) tmp[j] = 0.f;
      }
#pragma unroll
      for (int j = 0; j < 16; j++) At[(sq * 16 + j) * 64 + sr] = tmp[j];
    }
    for (int i = tid * 4; i < 64 * NN; i += 1024)
      *(float4*)&Wl[i] = *(const float4*)(W + (long)k0 * NN + i);
    __syncthreads();
#pragma unroll 4
    for (int k = 0; k < 64; k++) {
      float4 a4 = *(const float4*)&At[k * 64 + rg * 4];
      float av[4] = {a4.x, a4.y, a4.z, a4.w};
#pragma unroll
      for (int b = 0; b < CPT / 4; b++) {
        float4 w4 = *(const float4*)&Wl[k * NN + cg * CPT + b * 4];
        float wv[4] = {w4.x, w4.y, w4.z, w4.w};
#pragma unroll
        for (int i = 0; i < 4; i++)
#pragma unroll
          for (int c = 0; c < 4; c++) acc[i][b * 4 + c] += av[i] * wv[c];
      }
    }
    __syncthreads();
  }
#pragma unroll
  for (int i = 0; i < 4; i++) {
    long row = row0 + rg * 4 + i;
    if (row < M) {
#pragma unroll
      for (int b = 0; b < CPT / 4; b++) {
        float4 o; o.x = acc[i][b*4]; o.y = acc[i][b*4+1]; o.z = acc[i][b*4+2]; o.w = acc[i][b*4+3];
        *(float4*)(Cc + row * NN + cg * CPT + b * 4) = o;
      }
    }
  }
}

// ---- CSR gather aggregation, 4-deep neighbor unroll for outstanding loads ----
template<int C, bool OUTBF>
__global__ void k_agg(const float* __restrict__ xw, const float* __restrict__ dinv,
                      const int* __restrict__ rs, const int* __restrict__ csr,
                      const float* __restrict__ bias, void* __restrict__ outp, int Nn) {
  int wid = (blockIdx.x * 256 + threadIdx.x) >> 6;
  int lane = threadIdx.x & 63;
  int n, ch;
  if (C == 128) { n = wid >> 1; ch = ((wid & 1) << 6) + lane; }
  else         { n = wid;      ch = lane; }
  if (n >= Nn) return;
  int p0 = rs[n], p1 = rs[n + 1];
  float acc = 0.f;
  int p = p0;
  for (; p + 4 <= p1; p += 4) {
    int s0 = csr[p], s1 = csr[p + 1], s2 = csr[p + 2], s3 = csr[p + 3];
    float v0 = dinv[s0] * xw[(long)s0 * C + ch];
    float v1 = dinv[s1] * xw[(long)s1 * C + ch];
    float v2 = dinv[s2] * xw[(long)s2 * C + ch];
    float v3 = dinv[s3] * xw[(long)s3 * C + ch];
    acc += (v0 + v1) + (v2 + v3);
  }
  for (; p < p1; ++p) {
    int s = csr[p];
    acc += dinv[s] * xw[(long)s * C + ch];
  }
  float di = dinv[n];
  float v = fmaxf(di * acc + di * di * xw[(long)n * C + ch] + bias[ch], 0.f);
  if (OUTBF) ((unsigned short*)outp)[(long)n * C + ch] = f2bf(v);
  else       ((float*)outp)[(long)n * C + ch] = v;
}

// ---- MFMA edge scorer: wave = 16 label rows ----
__global__ __launch_bounds__(256)
void k_edge(const float* __restrict__ h2, const int* __restrict__ lab, int L,
            const unsigned short* __restrict__ w1s, const float* __restrict__ b1f,
            const float* __restrict__ w2f, const float* __restrict__ b2f,
            void* __restrict__ out, const int* __restrict__ modep) {
  int lane = threadIdx.x & 63;
  int tile = blockIdx.x * 4 + (threadIdx.x >> 6);
  long row0 = (long)tile * 16;
  if (row0 >= L) return;
  int quad = lane >> 4, l16 = lane & 15;
  long r = row0 + l16; if (r >= L) r = L - 1;   // clamp tail loads
  int a = lab[r], b = lab[L + r];
  const int md = *modep;
  f32x4 acc[4] = {};
#pragma unroll
  for (int s = 0; s < 2; ++s) {
    int c0 = s * 32 + quad * 8;
    const float* pa = h2 + (long)a * 64 + c0;
    const float* pb = h2 + (long)b * 64 + c0;
    float4 x0 = *(const float4*)pa, x1 = *(const float4*)(pa + 4);
    float4 y0 = *(const float4*)pb, y1 = *(const float4*)(pb + 4);
    s16x8 af;
    af[0] = (short)f2bf(x0.x * y0.x); af[1] = (short)f2bf(x0.y * y0.y);
    af[2] = (short)f2bf(x0.z * y0.z); af[3] = (short)f2bf(x0.w * y0.w);
    af[4] = (short)f2bf(x1.x * y1.x); af[5] = (short)f2bf(x1.y * y1.y);
    af[6] = (short)f2bf(x1.z * y1.z); af[7] = (short)f2bf(x1.w * y1.w);
#pragma unroll
    for (int t = 0; t < 4; ++t) {
      s16x8 bfr = *((const s16x8*)w1s + ((t * 2 + s) * 64 + lane));
      acc[t] = __builtin_amdgcn_mfma_f32_16x16x32_bf16(af, bfr, acc[t], 0, 0, 0);
    }
  }
  float ob0 = b2f[0], ob1 = b2f[1];
  float bb[4], w20[4], w21[4];
#pragma unroll
  for (int t = 0; t < 4; ++t) {
    int j = t * 16 + l16;
    bb[t]  = b1f[j];
    w20[t] = w2f[j * 2];
    w21[t] = w2f[j * 2 + 1];
  }
#pragma unroll
  for (int rr = 0; rr < 4; ++rr) {
    float p0 = 0.f, p1 = 0.f;
#pragma unroll
    for (int t = 0; t < 4; ++t) {
      float z = fmaxf(acc[t][rr] + bb[t], 0.f);
      p0 += z * w20[t];
      p1 += z * w21[t];
    }
#pragma unroll
    for (int off = 1; off < 16; off <<= 1) {   // reduce 16 lanes within quad
      p0 += __shfl_xor(p0, off, 64);
      p1 += __shfl_xor(p1, off, 64);
    }
    long row = row0 + quad * 4 + rr;
    if (l16 == 0 && row < L) {
      if (md) {
        unsigned pack = (unsigned)f2bf(p0 + ob0) | ((unsigned)f2bf(p1 + ob1) << 16);
        ((unsigned*)out)[row] = pack;
      } else {
        float2 o; o.x = p0 + ob0; o.y = p1 + ob1;
        ((float2*)out)[row] = o;
      }
    }
  }
}

extern "C" void kernel_launch(void* const* d_in, const int* in_sizes, int n_in,
                              void* d_out, int out_size, void* d_ws, size_t ws_size,
                              hipStream_t stream) {
  const void* x    = d_in[0];
  const void* W1   = d_in[1];
  const void* b1   = d_in[2];
  const void* W2   = d_in[3];
  const void* b2   = d_in[4];
  const void* fcW1 = d_in[5];
  const void* fcb1 = d_in[6];
  const void* fcW2 = d_in[7];
  const void* fcb2 = d_in[8];
  const int* eidx = (const int*)d_in[9];
  const int* lidx = (const int*)d_in[10];

  const int Nn = in_sizes[0] / 512;   // 100000
  const int E  = in_sizes[9] / 2;     // 3200000
  const int L  = in_sizes[10] / 2;    // 1000000

  char* ws = (char*)d_ws;
  size_t off = 0;
  auto alloc = [&](size_t bytes) { size_t o = off; off += (bytes + 15) & ~(size_t)15; return o; };

  size_t o_seg0 = alloc((size_t)Nn * 128 * 4);
  float* xw1 = (float*)(ws + o_seg0);
  float* h2  = (float*)(ws + o_seg0);
  float* hw2 = (float*)(ws + o_seg0 + (size_t)Nn * 64 * 4);
  unsigned short* h1 = (unsigned short*)(ws + alloc((size_t)Nn * 128 * 2));
  int*   cnts = (int*)(ws + alloc((size_t)Nn * 4));
  int*   rs   = (int*)(ws + alloc((size_t)(Nn + 1) * 4));
  int*   cur  = (int*)(ws + alloc((size_t)Nn * 4));
  int*   csr  = (int*)(ws + alloc((size_t)E * 4));
  float* dinv = (float*)(ws + alloc((size_t)Nn * 4));
  float* W1f   = (float*)(ws + alloc(512 * 128 * 4));
  float* W2f   = (float*)(ws + alloc(128 * 64 * 4));
  float* fcW1f = (float*)(ws + alloc(64 * 64 * 4));
  float* fcW2f = (float*)(ws + alloc(64 * 2 * 4));
  float* b1f   = (float*)(ws + alloc(128 * 4));
  float* b2f   = (float*)(ws + alloc(64 * 4));
  float* fcb1f = (float*)(ws + alloc(64 * 4));
  float* fcb2f = (float*)(ws + alloc(16));
  unsigned short* w1s = (unsigned short*)(ws + alloc(64 * 64 * 2));
  int*   mode  = (int*)(ws + alloc(16));

  k_probe<<<1, 256, 0, stream>>>(x, mode);
  k_cvt<<<(512 * 128 + 255) / 256, 256, 0, stream>>>(W1, W1f, 512 * 128, mode);
  k_cvt<<<(128 * 64 + 255) / 256, 256, 0, stream>>>(W2, W2f, 128 * 64, mode);
  k_cvt<<<(64 * 64 + 255) / 256, 256, 0, stream>>>(fcW1, fcW1f, 64 * 64, mode);
  k_cvt<<<1, 256, 0, stream>>>(fcW2, fcW2f, 64 * 2, mode);
  k_cvt<<<1, 256, 0, stream>>>(b1, b1f, 128, mode);
  k_cvt<<<1, 256, 0, stream>>>(b2, b2f, 64, mode);
  k_cvt<<<1, 256, 0, stream>>>(fcb1, fcb1f, 64, mode);
  k_cvt<<<1, 256, 0, stream>>>(fcb2, fcb2f, 2, mode);
  k_swz_bf<<<(64 * 64 + 255) / 256, 256, 0, stream>>>(fcW1f, w1s, 64, 2, 64 * 64);

  k_zero2<<<(Nn + 255) / 256, 256, 0, stream>>>(cnts, cur, Nn);
  k_count<<<(E + 255) / 256, 256, 0, stream>>>(eidx + E, cnts, E);
  k_scan<<<1, 1024, 0, stream>>>(cnts, rs, Nn);
  k_dinv<<<(Nn + 255) / 256, 256, 0, stream>>>(cnts, dinv, Nn);
  k_fill<<<(E + 255) / 256, 256, 0, stream>>>(eidx, eidx + E, rs, cur, csr, E);

  const int gB = (Nn + 63) / 64;
  k_gemm<512, 128, false><<<gB, 256, 0, stream>>>(x, W1f, xw1, Nn, mode);
  k_agg<128, true><<<(2 * Nn * 64 + 255) / 256, 256, 0, stream>>>(xw1, dinv, rs, csr, b1f, h1, Nn);
  k_gemm<128, 64, true><<<gB, 256, 0, stream>>>(h1, W2f, hw2, Nn, mode);
  k_agg<64, false><<<(Nn * 64 + 255) / 256, 256, 0, stream>>>(hw2, dinv, rs, csr, b2f, h2, Nn);

  const int tilesL = (L + 15) / 16;
  k_edge<<<(tilesL + 3) / 4, 256, 0, stream>>>(h2, lidx, L, w1s, fcb1f, fcW2f, fcb2f, d_out, mode);
}